// Round 3
// baseline (400.706 us; speedup 1.0000x reference)
//
#include <hip/hip_runtime.h>

// Deformable conv2d fp32 baseline.
// x:      (2, 64, 128, 256)
// offset: (2, 18, 128, 256)   ch = 2*k (+0=y, +1=x), k = 3*ki+kj
// weight: (64, 64, 3, 3)
// bias:   (64,)
// out:    (2, 64, 128, 256)

constexpr int Bn = 2, CI = 64, HI = 128, WI = 256;
constexpr int CO = 64, KKc = 9, HO = 128, WO = 256;
constexpr int HWi = HI * WI;          // 32768, same as HO*WO
constexpr int OPB = 32;               // Cout per block (2 groups)

__global__ __launch_bounds__(256, 2) void deform_conv_kernel(
    const float* __restrict__ x, const float* __restrict__ off,
    const float* __restrict__ wgt, const float* __restrict__ bias,
    float* __restrict__ out)
{
    const int wo  = threadIdx.x;          // 0..255 == WO
    const int row = blockIdx.x;           // 0..255 == b*HO+ho
    const int b   = row >> 7;
    const int ho  = row & 127;
    const int og  = blockIdx.y * OPB;     // Cout group base

    float acc[OPB];
    #pragma unroll
    for (int o = 0; o < OPB; ++o) acc[o] = bias[og + o];

    const float* xb   = x + b * CI * HWi;
    const float* offp = off + ((b * 2 * KKc) * HO + ho) * WO + wo;

    #pragma unroll 1
    for (int k = 0; k < KKc; ++k) {
        const int ki = k / 3, kj = k - 3 * ki;
        const float offY = offp[(2 * k) * HO * WO];
        const float offX = offp[(2 * k + 1) * HO * WO];
        const float py = (float)(ho - 1 + ki) + offY;
        const float px = (float)(wo - 1 + kj) + offX;
        const float y0f = floorf(py), x0f = floorf(px);
        const float wy = py - y0f, wx = px - x0f;
        const int y0 = (int)y0f, x0 = (int)x0f;
        const int y1 = y0 + 1,   x1 = x0 + 1;
        const float vy0 = (y0 >= 0 && y0 < HI) ? 1.f : 0.f;
        const float vy1 = (y1 >= 0 && y1 < HI) ? 1.f : 0.f;
        const float vx0 = (x0 >= 0 && x0 < WI) ? 1.f : 0.f;
        const float vx1 = (x1 >= 0 && x1 < WI) ? 1.f : 0.f;
        const int cy0 = min(max(y0, 0), HI - 1), cy1 = min(max(y1, 0), HI - 1);
        const int cx0 = min(max(x0, 0), WI - 1), cx1 = min(max(x1, 0), WI - 1);
        // fold corner validity into bilinear weights (ref multiplies by valid)
        const float w00 = (1.f - wy) * (1.f - wx) * vy0 * vx0;
        const float w01 = (1.f - wy) * wx         * vy0 * vx1;
        const float w10 = wy         * (1.f - wx) * vy1 * vx0;
        const float w11 = wy         * wx         * vy1 * vx1;
        const int i00 = cy0 * WI + cx0, i01 = cy0 * WI + cx1;
        const int i10 = cy1 * WI + cx0, i11 = cy1 * WI + cx1;

        const float* wk = wgt + og * CI * KKc + k;   // + c*9 + o*576

        #pragma unroll 1
        for (int c = 0; c < CI; ++c) {
            const float* xc = xb + c * HWi;
            float s = xc[i00] * w00;
            s = fmaf(xc[i01], w01, s);
            s = fmaf(xc[i10], w10, s);
            s = fmaf(xc[i11], w11, s);
            const float* wc = wk + c * KKc;          // uniform → s_load expected
            #pragma unroll
            for (int o = 0; o < OPB; ++o)
                acc[o] = fmaf(s, wc[o * CI * KKc], acc[o]);
        }
    }

    float* po = out + ((b * CO + og) * HO + ho) * WO + wo;
    #pragma unroll
    for (int o = 0; o < OPB; ++o) po[o * HWi] = acc[o];
}

extern "C" void kernel_launch(void* const* d_in, const int* in_sizes, int n_in,
                              void* d_out, int out_size, void* d_ws, size_t ws_size,
                              hipStream_t stream) {
    const float* x    = (const float*)d_in[0];
    const float* off  = (const float*)d_in[1];
    const float* wgt  = (const float*)d_in[2];
    const float* bias = (const float*)d_in[3];
    float* out = (float*)d_out;
    dim3 grid(Bn * HO, CO / OPB);   // (256, 2)
    deform_conv_kernel<<<grid, dim3(256, 1, 1), 0, stream>>>(x, off, wgt, bias, out);
}

// Round 4
// 255.066 us; speedup vs baseline: 1.5710x; 1.5710x over previous
//
#include <hip/hip_runtime.h>
#include <hip/hip_bf16.h>

// Deformable conv2d — fused bf16-MFMA im2col.
// x:(2,64,128,256) off:(2,18,128,256) wgt:(64,64,3,3) bias:(64) out:(2,64,128,256)
// Block: 256 thr (4 waves), tile = 4 ho x 16 wo = 64 px, all 64 Cout.
// K = c*kk = 576 ordered k-major: 9 chunks of 64 (one tap k, all 64 c).

constexpr int CI = 64, HI = 128, WI = 256;
constexpr int CO = 64, KK = 9, HO = 128, WO = 256;
constexpr int HWi = HI * WI;   // 32768
constexpr int HWo = HO * WO;   // 32768

typedef __attribute__((ext_vector_type(4))) float f32x4;
typedef __attribute__((ext_vector_type(8))) short s16x8;

__device__ __forceinline__ short to_bf16(float f) {
    __hip_bfloat16 h = __float2bfloat16(f);
    return *reinterpret_cast<short*>(&h);
}

__global__ __launch_bounds__(256, 4) void dconv_mfma(
    const float* __restrict__ x, const float* __restrict__ off,
    const float* __restrict__ wgt, const float* __restrict__ bias,
    float* __restrict__ out)
{
    __shared__ short sW[64 * 64];        // [m][c] bf16, XOR-swizzled rows (128B)
    __shared__ short sS[64 * 64];        // [px][c] bf16, XOR-swizzled rows
    __shared__ float pw[4][KK * 64];     // bilinear weights, SoA [k][n]
    __shared__ int   pidx[4][KK * 64];   // corner byte-offsets within channel plane

    const int tid  = threadIdx.x;
    const int lane = tid & 63;
    const int wv   = tid >> 6;

    // XCD-aware swizzle: 1024 blocks = 8 XCDs x 128 contiguous tiles
    const int wg  = ((blockIdx.x & 7) << 7) | (blockIdx.x >> 3);
    const int b   = wg >> 9;             // batch
    const int hot = (wg >> 4) & 31;
    const int wot = wg & 15;
    const int ho0 = hot * 4, wo0 = wot * 16;

    // ---- phase 0: bilinear params for 9 taps x 64 px ----
    const float* offb = off + (size_t)b * (2 * KK * HWo);
    for (int e = tid; e < KK * 64; e += 256) {
        const int k  = e >> 6;
        const int n  = e & 63;
        const int pr = n >> 4, pc = n & 15;
        const int ho = ho0 + pr, wo = wo0 + pc;
        const int ki = k / 3, kj = k - 3 * ki;
        const float oy = offb[(2 * k) * HWo + ho * WO + wo];
        const float ox = offb[(2 * k + 1) * HWo + ho * WO + wo];
        const float py  = (float)(ho - 1 + ki) + oy;
        const float pxx = (float)(wo - 1 + kj) + ox;
        const float y0f = floorf(py), x0f = floorf(pxx);
        const float wy = py - y0f, wx = pxx - x0f;
        const int y0 = (int)y0f, x0 = (int)x0f;
        const int y1 = y0 + 1, x1 = x0 + 1;
        const float vy0 = (y0 >= 0 && y0 < HI) ? 1.f : 0.f;
        const float vy1 = (y1 >= 0 && y1 < HI) ? 1.f : 0.f;
        const float vx0 = (x0 >= 0 && x0 < WI) ? 1.f : 0.f;
        const float vx1 = (x1 >= 0 && x1 < WI) ? 1.f : 0.f;
        const int cy0 = min(max(y0, 0), HI - 1), cy1 = min(max(y1, 0), HI - 1);
        const int cx0 = min(max(x0, 0), WI - 1), cx1 = min(max(x1, 0), WI - 1);
        pw[0][e] = (1.f - wy) * (1.f - wx) * vy0 * vx0;
        pw[1][e] = (1.f - wy) * wx         * vy0 * vx1;
        pw[2][e] = wy         * (1.f - wx) * vy1 * vx0;
        pw[3][e] = wy         * wx         * vy1 * vx1;
        pidx[0][e] = (cy0 * WI + cx0) * 4;
        pidx[1][e] = (cy0 * WI + cx1) * 4;
        pidx[2][e] = (cy1 * WI + cx0) * 4;
        pidx[3][e] = (cy1 * WI + cx1) * 4;
    }

    // accumulators init with bias: D row m = 16*wv + 4*(lane>>4) + r, col n = 16f + (lane&15)
    f32x4 acc[4];
    {
        const int r0 = 16 * wv + 4 * (lane >> 4);
        f32x4 ini;
        ini[0] = bias[r0]; ini[1] = bias[r0 + 1];
        ini[2] = bias[r0 + 2]; ini[3] = bias[r0 + 3];
        #pragma unroll
        for (int f = 0; f < 4; ++f) acc[f] = ini;
    }
    __syncthreads();

    const char* xb = (const char*)(x + (size_t)b * CI * HWi);
    const int mst = tid >> 2;            // W-staging row (Cout)
    const int cst = (tid & 3) * 16;      // W-staging c base
    const float* wrow = wgt + (size_t)mst * (CI * KK);

    for (int k = 0; k < KK; ++k) {
        if (k) __syncthreads();          // prev chunk's MFMA reads done

        // --- stage W tap-slice: sW[m][c] = bf16(W[m][c][k]) ---
        #pragma unroll
        for (int g = 0; g < 2; ++g) {
            s16x8 v;
            #pragma unroll
            for (int j = 0; j < 8; ++j)
                v[j] = to_bf16(wrow[(cst + 8 * g + j) * KK + k]);
            char* p = (char*)sW + ((mst * 128 + 2 * (cst + 8 * g)) ^ ((mst & 7) << 4));
            *(s16x8*)p = v;
        }

        // --- sample S tap-slice: sS[px=lane][c], wave wv does c=16wv..16wv+15 ---
        const float w0 = pw[0][k * 64 + lane], w1 = pw[1][k * 64 + lane];
        const float w2 = pw[2][k * 64 + lane], w3 = pw[3][k * 64 + lane];
        const int  i0 = pidx[0][k * 64 + lane], i1 = pidx[1][k * 64 + lane];
        const int  i2 = pidx[2][k * 64 + lane], i3 = pidx[3][k * 64 + lane];
        #pragma unroll
        for (int g = 0; g < 2; ++g) {
            s16x8 v;
            #pragma unroll
            for (int j = 0; j < 8; ++j) {
                const char* bc = xb + (size_t)(16 * wv + 8 * g + j) * (HWi * 4);
                float s = *(const float*)(bc + i0) * w0
                        + *(const float*)(bc + i1) * w1
                        + *(const float*)(bc + i2) * w2
                        + *(const float*)(bc + i3) * w3;
                v[j] = to_bf16(s);
            }
            char* p = (char*)sS + ((lane * 128 + 2 * (16 * wv + 8 * g)) ^ ((lane & 7) << 4));
            *(s16x8*)p = v;
        }
        __syncthreads();

        // --- MFMA: wave wv owns M rows 16wv..16wv+15, 4 N-frags, 2 K-steps ---
        const int mrow = 16 * wv + (lane & 15);
        const int koff = 16 * (lane >> 4);
        const int xr   = (lane & 7) << 4;
        const s16x8 a0 = *(const s16x8*)((const char*)sW + ((mrow * 128 + koff) ^ xr));
        const s16x8 a1 = *(const s16x8*)((const char*)sW + ((mrow * 128 + 64 + koff) ^ xr));
        #pragma unroll
        for (int f = 0; f < 4; ++f) {
            const int nrow = 16 * f + (lane & 15);
            const s16x8 b0 = *(const s16x8*)((const char*)sS + ((nrow * 128 + koff) ^ xr));
            const s16x8 b1 = *(const s16x8*)((const char*)sS + ((nrow * 128 + 64 + koff) ^ xr));
            acc[f] = __builtin_amdgcn_mfma_f32_16x16x32_bf16(a0, b0, acc[f], 0, 0, 0);
            acc[f] = __builtin_amdgcn_mfma_f32_16x16x32_bf16(a1, b1, acc[f], 0, 0, 0);
        }
    }

    // --- store: n = 16f + (lane&15) -> pr = f, pc = lane&15 (contiguous wo) ---
    #pragma unroll
    for (int f = 0; f < 4; ++f) {
        const int ho = ho0 + f;
        const int wo = wo0 + (lane & 15);
        const int m0 = 16 * wv + 4 * (lane >> 4);
        float* po = out + (((size_t)(b * CO + m0) * HO + ho) * WO + wo);
        #pragma unroll
        for (int r = 0; r < 4; ++r)
            po[(size_t)r * HWo] = acc[f][r];
    }
}

extern "C" void kernel_launch(void* const* d_in, const int* in_sizes, int n_in,
                              void* d_out, int out_size, void* d_ws, size_t ws_size,
                              hipStream_t stream) {
    const float* x    = (const float*)d_in[0];
    const float* off  = (const float*)d_in[1];
    const float* wgt  = (const float*)d_in[2];
    const float* bias = (const float*)d_in[3];
    float* out = (float*)d_out;
    dconv_mfma<<<dim3(1024), dim3(256), 0, stream>>>(x, off, wgt, bias, out);
}

// Round 11
// 103.126 us; speedup vs baseline: 3.8856x; 2.4733x over previous
//
#include <hip/hip_runtime.h>
#include <hip/hip_bf16.h>

// Deformable conv2d — NHWC-bf16 prepass + fused MFMA im2col.
// x:(2,64,128,256) off:(2,18,128,256) wgt:(64,64,3,3) bias:(64) out:(2,64,128,256)
// ws layout: xt = NHWC bf16 (2*32768*64*2 = 8 MB) | wp = bf16 [k][m][c] (72 KB)

constexpr int CI = 64, HI = 128, WI = 256;
constexpr int CO = 64, KK = 9, HO = 128, WO = 256;
constexpr int HWi = HI * WI;   // 32768
constexpr int HWo = HO * WO;   // 32768

typedef __attribute__((ext_vector_type(4))) float f32x4;
typedef __attribute__((ext_vector_type(8))) short s16x8;
typedef __attribute__((ext_vector_type(4))) unsigned int u32x4;

__device__ __forceinline__ short to_bf16(float f) {
    __hip_bfloat16 h = __float2bfloat16(f);
    return *reinterpret_cast<short*>(&h);
}
__device__ __forceinline__ float bf2f(short s) {
    unsigned int u = ((unsigned int)(unsigned short)s) << 16;
    return __uint_as_float(u);
}

// ---- prepass 1: x NCHW fp32 -> NHWC bf16 ----
__global__ __launch_bounds__(256, 2) void xpose(
    const float* __restrict__ x, short* __restrict__ xt)
{
    __shared__ short st[256 * 66];              // row stride 66 shorts (33 dw)
    const int tid = threadIdx.x;
    const int px0 = blockIdx.x * 256;           // global pixel (b*HWi + p)
    const int b = px0 >> 15;
    const float* xb = x + (size_t)b * CI * HWi + (px0 & (HWi - 1));
    #pragma unroll 8
    for (int c = 0; c < CI; ++c)
        st[tid * 66 + c] = to_bf16(xb[(size_t)c * HWi + tid]);   // coalesced read
    __syncthreads();
    const unsigned int* st32 = (const unsigned int*)st;
    #pragma unroll
    for (int r = 0; r < 4; ++r) {
        const int p = r * 64 + (tid >> 2), g = tid & 3;
        unsigned int v[8];
        #pragma unroll
        for (int j = 0; j < 8; ++j) v[j] = st32[p * 33 + g * 8 + j];
        unsigned int* dst = (unsigned int*)(xt + (size_t)(px0 + p) * 64 + g * 16);
        *(u32x4*)dst = u32x4{v[0], v[1], v[2], v[3]};
        *(u32x4*)(dst + 4) = u32x4{v[4], v[5], v[6], v[7]};      // coalesced write
    }
}

// ---- prepass 2: wgt (64,64,3,3) fp32 -> wp[k][m][c] bf16 ----
__global__ void wpack_k(const float* __restrict__ w, short* __restrict__ wp)
{
    const int e = blockIdx.x * 256 + threadIdx.x;
    if (e >= KK * CO * CI) return;
    const int k = e >> 12, rem = e & 4095;      // rem = m*64 + c
    wp[e] = to_bf16(w[(size_t)rem * KK + k]);
}

// ---- main: 64px x 64Cout tile, 9 k-chunks of K=64, bf16 MFMA ----
__global__ __launch_bounds__(256, 4) void dconv_mfma(
    const short* __restrict__ xt, const float* __restrict__ off,
    const short* __restrict__ wp, const float* __restrict__ bias,
    float* __restrict__ out)
{
    __shared__ short sS[64 * 64];               // [px][c] bf16, XOR-swizzled rows
    __shared__ float pw[4][KK * 64];
    __shared__ int   pidx[4][KK * 64];          // corner byte offset (NHWC, per batch)

    const int tid = threadIdx.x, lane = tid & 63, wv = tid >> 6;
    const int wg = ((blockIdx.x & 7) << 7) | (blockIdx.x >> 3);   // XCD swizzle
    const int b = wg >> 9, hot = (wg >> 4) & 31, wot = wg & 15;
    const int ho0 = hot * 4, wo0 = wot * 16;

    // phase 0: bilinear params for 9 taps x 64 px
    const float* offb = off + (size_t)b * (2 * KK * HWo);
    for (int e = tid; e < KK * 64; e += 256) {
        const int k = e >> 6, n = e & 63;
        const int ho = ho0 + (n >> 4), wo = wo0 + (n & 15);
        const int ki = k / 3, kj = k - 3 * ki;
        const float oy = offb[(2 * k) * HWo + ho * WO + wo];
        const float ox = offb[(2 * k + 1) * HWo + ho * WO + wo];
        const float py  = (float)(ho - 1 + ki) + oy;
        const float pxx = (float)(wo - 1 + kj) + ox;
        const float y0f = floorf(py), x0f = floorf(pxx);
        const float wy = py - y0f, wx = pxx - x0f;
        const int y0 = (int)y0f, x0 = (int)x0f;
        const int y1 = y0 + 1, x1 = x0 + 1;
        const float vy0 = (y0 >= 0 && y0 < HI) ? 1.f : 0.f;
        const float vy1 = (y1 >= 0 && y1 < HI) ? 1.f : 0.f;
        const float vx0 = (x0 >= 0 && x0 < WI) ? 1.f : 0.f;
        const float vx1 = (x1 >= 0 && x1 < WI) ? 1.f : 0.f;
        const int cy0 = min(max(y0, 0), HI - 1), cy1 = min(max(y1, 0), HI - 1);
        const int cx0 = min(max(x0, 0), WI - 1), cx1 = min(max(x1, 0), WI - 1);
        pw[0][e] = (1.f - wy) * (1.f - wx) * vy0 * vx0;
        pw[1][e] = (1.f - wy) * wx         * vy0 * vx1;
        pw[2][e] = wy         * (1.f - wx) * vy1 * vx0;
        pw[3][e] = wy         * wx         * vy1 * vx1;
        pidx[0][e] = (cy0 * WI + cx0) * 128;    // *64ch*2B
        pidx[1][e] = (cy0 * WI + cx1) * 128;
        pidx[2][e] = (cy1 * WI + cx0) * 128;
        pidx[3][e] = (cy1 * WI + cx1) * 128;
    }

    f32x4 acc[4];
    {
        const int r0 = 16 * wv + 4 * (lane >> 4);
        const f32x4 ini = *(const f32x4*)(bias + r0);
        #pragma unroll
        for (int f = 0; f < 4; ++f) acc[f] = ini;
    }
    __syncthreads();

    const char* xtb = (const char*)xt + (size_t)b * HWi * 128;
    const int px = tid >> 2, cg = tid & 3, cb = cg * 32;
    const int mrow = 16 * wv + (lane & 15);
    const int ke = 8 * (lane >> 4);             // element offset into K-slice
    const int koffb = 16 * (lane >> 4);         // byte offset for B-frag reads
    const int xr = (lane & 7) << 4;

    for (int k = 0; k < KK; ++k) {
        if (k) __syncthreads();                 // prev MFMA readers done

        // A-frags direct from packed global (L2-resident), issued early
        const short* wpk = wp + k * 4096;
        const s16x8 a0 = *(const s16x8*)(wpk + mrow * 64 + ke);
        const s16x8 a1 = *(const s16x8*)(wpk + mrow * 64 + 32 + ke);

        // sample: 4 corners x 16 channels, quarter-wave-coalesced b128 loads
        float a[16];
        #pragma unroll
        for (int j = 0; j < 16; ++j) a[j] = 0.f;
        #pragma unroll
        for (int c4 = 0; c4 < 4; ++c4) {
            const float wc = pw[c4][k * 64 + px];
            const int ofs = pidx[c4][k * 64 + px];
            const s16x8 u0 = *(const s16x8*)(xtb + ofs + cb);
            const s16x8 u1 = *(const s16x8*)(xtb + ofs + cb + 16);
            #pragma unroll
            for (int j = 0; j < 8; ++j) {
                a[j]     = fmaf(wc, bf2f(u0[j]), a[j]);
                a[8 + j] = fmaf(wc, bf2f(u1[j]), a[8 + j]);
            }
        }
        s16x8 v0, v1;
        #pragma unroll
        for (int j = 0; j < 8; ++j) { v0[j] = to_bf16(a[j]); v1[j] = to_bf16(a[8 + j]); }
        *(s16x8*)((char*)sS + ((px * 128 + cb) ^ ((px & 7) << 4))) = v0;
        *(s16x8*)((char*)sS + ((px * 128 + cb + 16) ^ ((px & 7) << 4))) = v1;
        __syncthreads();                        // sS ready

        #pragma unroll
        for (int f = 0; f < 4; ++f) {
            const int nrow = 16 * f + (lane & 15);
            const s16x8 b0 = *(const s16x8*)((const char*)sS + ((nrow * 128 + koffb) ^ xr));
            const s16x8 b1 = *(const s16x8*)((const char*)sS + ((nrow * 128 + 64 + koffb) ^ xr));
            acc[f] = __builtin_amdgcn_mfma_f32_16x16x32_bf16(a0, b0, acc[f], 0, 0, 0);
            acc[f] = __builtin_amdgcn_mfma_f32_16x16x32_bf16(a1, b1, acc[f], 0, 0, 0);
        }
    }

    #pragma unroll
    for (int f = 0; f < 4; ++f) {
        const int ho = ho0 + f;
        const int wo = wo0 + (lane & 15);
        const int m0 = 16 * wv + 4 * (lane >> 4);
        float* po = out + (((size_t)(b * CO + m0) * HO + ho) * WO + wo);
        #pragma unroll
        for (int r = 0; r < 4; ++r)
            po[(size_t)r * HWo] = acc[f][r];
    }
}

extern "C" void kernel_launch(void* const* d_in, const int* in_sizes, int n_in,
                              void* d_out, int out_size, void* d_ws, size_t ws_size,
                              hipStream_t stream) {
    const float* x    = (const float*)d_in[0];
    const float* off  = (const float*)d_in[1];
    const float* wgt  = (const float*)d_in[2];
    const float* bias = (const float*)d_in[3];
    float* out = (float*)d_out;
    short* xt = (short*)d_ws;                                   // 8 MB
    short* wp = (short*)((char*)d_ws + (size_t)2 * HWi * 64 * 2);
    xpose<<<dim3(256), dim3(256), 0, stream>>>(x, xt);
    wpack_k<<<dim3(144), dim3(256), 0, stream>>>(wgt, wp);
    dconv_mfma<<<dim3(1024), dim3(256), 0, stream>>>(xt, off, wp, bias, out);
}

// Round 12
// 100.826 us; speedup vs baseline: 3.9742x; 1.0228x over previous
//
#include <hip/hip_runtime.h>
#include <hip/hip_bf16.h>

// Deformable conv2d — NHWC-bf16 prepass + fused MFMA im2col, T14-pipelined.
// x:(2,64,128,256) off:(2,18,128,256) wgt:(64,64,3,3) bias:(64) out:(2,64,128,256)
// ws: xt = NHWC bf16 (8 MB) | wp = bf16 [k][m][c] (72 KB)
// Main loop: prefetch chunk k+1 sample/weight loads into regs before the
// single per-chunk barrier; LDS sS double-buffered (write buf p, barrier,
// MFMA reads buf p while next iter writes buf p^1 — wave can't lap a buffer
// without passing the barrier every other wave holds).

constexpr int CI = 64, HI = 128, WI = 256;
constexpr int CO = 64, KK = 9, HO = 128, WO = 256;
constexpr int HWi = HI * WI;   // 32768
constexpr int HWo = HO * WO;   // 32768

typedef __attribute__((ext_vector_type(4))) float f32x4;
typedef __attribute__((ext_vector_type(8))) short s16x8;
typedef __attribute__((ext_vector_type(4))) unsigned int u32x4;

__device__ __forceinline__ short to_bf16(float f) {
    __hip_bfloat16 h = __float2bfloat16(f);
    return *reinterpret_cast<short*>(&h);
}
__device__ __forceinline__ float bf2f(short s) {
    unsigned int u = ((unsigned int)(unsigned short)s) << 16;
    return __uint_as_float(u);
}

// ---- prepass 1: x NCHW fp32 -> NHWC bf16 ----
__global__ __launch_bounds__(256, 2) void xpose(
    const float* __restrict__ x, short* __restrict__ xt)
{
    __shared__ short st[256 * 66];              // row stride 66 shorts (33 dw)
    const int tid = threadIdx.x;
    const int px0 = blockIdx.x * 256;           // global pixel (b*HWi + p)
    const int b = px0 >> 15;
    const float* xb = x + (size_t)b * CI * HWi + (px0 & (HWi - 1));
    #pragma unroll 8
    for (int c = 0; c < CI; ++c)
        st[tid * 66 + c] = to_bf16(xb[(size_t)c * HWi + tid]);   // coalesced read
    __syncthreads();
    const unsigned int* st32 = (const unsigned int*)st;
    #pragma unroll
    for (int r = 0; r < 4; ++r) {
        const int p = r * 64 + (tid >> 2), g = tid & 3;
        unsigned int v[8];
        #pragma unroll
        for (int j = 0; j < 8; ++j) v[j] = st32[p * 33 + g * 8 + j];
        unsigned int* dst = (unsigned int*)(xt + (size_t)(px0 + p) * 64 + g * 16);
        *(u32x4*)dst = u32x4{v[0], v[1], v[2], v[3]};
        *(u32x4*)(dst + 4) = u32x4{v[4], v[5], v[6], v[7]};      // coalesced write
    }
}

// ---- prepass 2: wgt (64,64,3,3) fp32 -> wp[k][m][c] bf16 ----
__global__ void wpack_k(const float* __restrict__ w, short* __restrict__ wp)
{
    const int e = blockIdx.x * 256 + threadIdx.x;
    if (e >= KK * CO * CI) return;
    const int k = e >> 12, rem = e & 4095;      // rem = m*64 + c
    wp[e] = to_bf16(w[(size_t)rem * KK + k]);
}

// ---- main: 64px x 64Cout tile, 9 k-chunks of K=64, bf16 MFMA, pipelined ----
__global__ __launch_bounds__(256, 4) void dconv_mfma(
    const short* __restrict__ xt, const float* __restrict__ off,
    const short* __restrict__ wp, const float* __restrict__ bias,
    float* __restrict__ out)
{
    __shared__ short sS[2][64 * 64];            // dbuf [px][c] bf16, XOR-swizzled
    __shared__ float pw[4][KK * 64];
    __shared__ int   pidx[4][KK * 64];          // corner byte offset (NHWC, per batch)

    const int tid = threadIdx.x, lane = tid & 63, wv = tid >> 6;
    const int wg = ((blockIdx.x & 7) << 7) | (blockIdx.x >> 3);   // XCD swizzle
    const int b = wg >> 9, hot = (wg >> 4) & 31, wot = wg & 15;
    const int ho0 = hot * 4, wo0 = wot * 16;

    // phase 0: bilinear params for 9 taps x 64 px
    const float* offb = off + (size_t)b * (2 * KK * HWo);
    for (int e = tid; e < KK * 64; e += 256) {
        const int k = e >> 6, n = e & 63;
        const int ho = ho0 + (n >> 4), wo = wo0 + (n & 15);
        const int ki = k / 3, kj = k - 3 * ki;
        const float oy = offb[(2 * k) * HWo + ho * WO + wo];
        const float ox = offb[(2 * k + 1) * HWo + ho * WO + wo];
        const float py  = (float)(ho - 1 + ki) + oy;
        const float pxx = (float)(wo - 1 + kj) + ox;
        const float y0f = floorf(py), x0f = floorf(pxx);
        const float wy = py - y0f, wx = pxx - x0f;
        const int y0 = (int)y0f, x0 = (int)x0f;
        const int y1 = y0 + 1, x1 = x0 + 1;
        const float vy0 = (y0 >= 0 && y0 < HI) ? 1.f : 0.f;
        const float vy1 = (y1 >= 0 && y1 < HI) ? 1.f : 0.f;
        const float vx0 = (x0 >= 0 && x0 < WI) ? 1.f : 0.f;
        const float vx1 = (x1 >= 0 && x1 < WI) ? 1.f : 0.f;
        const int cy0 = min(max(y0, 0), HI - 1), cy1 = min(max(y1, 0), HI - 1);
        const int cx0 = min(max(x0, 0), WI - 1), cx1 = min(max(x1, 0), WI - 1);
        pw[0][e] = (1.f - wy) * (1.f - wx) * vy0 * vx0;
        pw[1][e] = (1.f - wy) * wx         * vy0 * vx1;
        pw[2][e] = wy         * (1.f - wx) * vy1 * vx0;
        pw[3][e] = wy         * wx         * vy1 * vx1;
        pidx[0][e] = (cy0 * WI + cx0) * 128;    // *64ch*2B
        pidx[1][e] = (cy0 * WI + cx1) * 128;
        pidx[2][e] = (cy1 * WI + cx0) * 128;
        pidx[3][e] = (cy1 * WI + cx1) * 128;
    }

    f32x4 acc[4];
    {
        const int r0 = 16 * wv + 4 * (lane >> 4);
        const f32x4 ini = *(const f32x4*)(bias + r0);
        #pragma unroll
        for (int f = 0; f < 4; ++f) acc[f] = ini;
    }
    __syncthreads();                            // pw/pidx ready

    const char* xtb = (const char*)xt + (size_t)b * HWi * 128;
    const int px = tid >> 2, cg = tid & 3, cb = cg * 32;
    const int mrow = 16 * wv + (lane & 15);
    const int ke = 8 * (lane >> 4);             // element offset into K-slice
    const int koffb = 16 * (lane >> 4);         // byte offset for B-frag reads
    const int xr = (lane & 7) << 4;
    const int swz0 = (px * 128 + cb) ^ ((px & 7) << 4);
    const int swz1 = (px * 128 + cb + 16) ^ ((px & 7) << 4);

    // prologue: issue chunk-0 loads
    s16x8 u[8], a0, a1;
    #pragma unroll
    for (int c4 = 0; c4 < 4; ++c4) {
        const int ofs = pidx[c4][px];           // k=0
        u[2 * c4]     = *(const s16x8*)(xtb + ofs + cb);
        u[2 * c4 + 1] = *(const s16x8*)(xtb + ofs + cb + 16);
    }
    a0 = *(const s16x8*)(wp + mrow * 64 + ke);
    a1 = *(const s16x8*)(wp + mrow * 64 + 32 + ke);

    int p = 0;
    for (int k = 0; k < KK; ++k) {
        // ---- finish sample k (consume u, latency already hidden) ----
        float s[16];
        #pragma unroll
        for (int j = 0; j < 16; ++j) s[j] = 0.f;
        #pragma unroll
        for (int c4 = 0; c4 < 4; ++c4) {
            const float wc = pw[c4][k * 64 + px];
            #pragma unroll
            for (int j = 0; j < 8; ++j) {
                s[j]     = fmaf(wc, bf2f(u[2 * c4][j]), s[j]);
                s[8 + j] = fmaf(wc, bf2f(u[2 * c4 + 1][j]), s[8 + j]);
            }
        }
        s16x8 v0, v1;
        #pragma unroll
        for (int j = 0; j < 8; ++j) { v0[j] = to_bf16(s[j]); v1[j] = to_bf16(s[8 + j]); }
        char* sp = (char*)sS[p];
        *(s16x8*)(sp + swz0) = v0;
        *(s16x8*)(sp + swz1) = v1;

        // ---- prefetch chunk k+1 into regs (in flight across barrier+MFMA) ----
        if (k + 1 < KK) {
            #pragma unroll
            for (int c4 = 0; c4 < 4; ++c4) {
                const int ofs = pidx[c4][(k + 1) * 64 + px];
                u[2 * c4]     = *(const s16x8*)(xtb + ofs + cb);
                u[2 * c4 + 1] = *(const s16x8*)(xtb + ofs + cb + 16);
            }
        }
        __syncthreads();                        // sS[p] ready for all waves

        // ---- MFMA k from sS[p] ----
        const char* spc = (const char*)sS[p];
        #pragma unroll
        for (int f = 0; f < 4; ++f) {
            const int nrow = 16 * f + (lane & 15);
            const s16x8 b0 = *(const s16x8*)(spc + ((nrow * 128 + koffb) ^ xr));
            const s16x8 b1 = *(const s16x8*)(spc + ((nrow * 128 + 64 + koffb) ^ xr));
            acc[f] = __builtin_amdgcn_mfma_f32_16x16x32_bf16(a0, b0, acc[f], 0, 0, 0);
            acc[f] = __builtin_amdgcn_mfma_f32_16x16x32_bf16(a1, b1, acc[f], 0, 0, 0);
        }
        if (k + 1 < KK) {                       // A-frags for k+1 (L2-resident)
            const short* wpk1 = wp + (k + 1) * 4096;
            a0 = *(const s16x8*)(wpk1 + mrow * 64 + ke);
            a1 = *(const s16x8*)(wpk1 + mrow * 64 + 32 + ke);
        }
        p ^= 1;                                 // next write goes to other buf
    }

    #pragma unroll
    for (int f = 0; f < 4; ++f) {
        const int ho = ho0 + f;
        const int wo = wo0 + (lane & 15);
        const int m0 = 16 * wv + 4 * (lane >> 4);
        float* po = out + (((size_t)(b * CO + m0) * HO + ho) * WO + wo);
        #pragma unroll
        for (int r = 0; r < 4; ++r)
            po[(size_t)r * HWo] = acc[f][r];
    }
}

extern "C" void kernel_launch(void* const* d_in, const int* in_sizes, int n_in,
                              void* d_out, int out_size, void* d_ws, size_t ws_size,
                              hipStream_t stream) {
    const float* x    = (const float*)d_in[0];
    const float* off  = (const float*)d_in[1];
    const float* wgt  = (const float*)d_in[2];
    const float* bias = (const float*)d_in[3];
    float* out = (float*)d_out;
    short* xt = (short*)d_ws;                                   // 8 MB
    short* wp = (short*)((char*)d_ws + (size_t)2 * HWi * 64 * 2);
    xpose<<<dim3(256), dim3(256), 0, stream>>>(x, xt);
    wpack_k<<<dim3(144), dim3(256), 0, stream>>>(wgt, wp);
    dconv_mfma<<<dim3(1024), dim3(256), 0, stream>>>(xt, off, wp, bias, out);
}